// Round 1
// baseline (246.447 us; speedup 1.0000x reference)
//
#include <hip/hip_runtime.h>
#include <stdint.h>

#define NN3 262144
#define NN2 65536
#define NN1 16384

typedef __attribute__((ext_vector_type(8))) __bf16 bf16x8;
typedef __attribute__((ext_vector_type(4))) float floatx4;

static __device__ __forceinline__ float bf2f(unsigned short u) {
    union { unsigned int i; float f; } v; v.i = ((unsigned int)u) << 16; return v.f;
}
static __device__ __forceinline__ unsigned short f2bf(float f) {
    union { float f; unsigned int i; } v; v.f = f;
    unsigned int x = v.i;
    return (unsigned short)((x + 0x7fffu + ((x >> 16) & 1u)) >> 16);
}
static __device__ __forceinline__ unsigned int umax32(unsigned int a, unsigned int b) { return a > b ? a : b; }
static __device__ __forceinline__ bf16x8 zero_bf16x8() {
    bf16x8 z;
#pragma unroll
    for (int i = 0; i < 8; ++i) z[i] = (__bf16)0.0f;
    return z;
}

// ---------------- prep: convert weights to bf16 + compute parent indices ----------------
__global__ __launch_bounds__(256) void prep_kernel(
    const float* __restrict__ w_enc2, const float* __restrict__ w_enc3,
    const float* __restrict__ w_dec1, const float* __restrict__ w_dec2,
    unsigned short* __restrict__ wb_enc2, unsigned short* __restrict__ wb_enc3,
    unsigned short* __restrict__ wb_dec1, unsigned short* __restrict__ wb_dec2,
    const int* __restrict__ keys3, const int* __restrict__ keys2, const int* __restrict__ keys1,
    int* __restrict__ pidx32, int* __restrict__ pidx21)
{
    int t = blockIdx.x * 256 + threadIdx.x;
    if (t < 4608)  { wb_enc2[t] = f2bf(w_enc2[t]); return; }
    t -= 4608;
    if (t < 18432) { wb_enc3[t] = f2bf(w_enc3[t]); return; }
    t -= 18432;
    if (t < 18432) { wb_dec1[t] = f2bf(w_dec1[t]); return; }
    t -= 18432;
    if (t < 4608)  { wb_dec2[t] = f2bf(w_dec2[t]); return; }
    t -= 4608;
    if (t < NN3) {
        int v = keys3[t] >> 2;
        int lo = 0, hi = NN2;
        while (lo < hi) { int m = (lo + hi) >> 1; if (keys2[m] < v) lo = m + 1; else hi = m; }
        pidx32[t] = lo < NN2 ? lo : NN2 - 1;
        return;
    }
    t -= NN3;
    if (t < NN2) {
        int v = keys2[t] >> 2;
        int lo = 0, hi = NN1;
        while (lo < hi) { int m = (lo + hi) >> 1; if (keys1[m] < v) lo = m + 1; else hi = m; }
        pidx21[t] = lo < NN1 ? lo : NN1 - 1;
    }
}

// ---------------- enc1: Cin=1 fp32 -> Cout=16 bf16, relu ----------------
__global__ __launch_bounds__(256) void enc1_kernel(
    const float* __restrict__ feat, const int* __restrict__ neigh,
    const float* __restrict__ w, const float* __restrict__ b,
    unsigned short* __restrict__ out)
{
    __shared__ float ws[144];
    __shared__ float bs[16];
    __shared__ int nsh[2304];
    int t = threadIdx.x;
    if (t < 144) ws[t] = w[t];
    if (t < 16)  bs[t] = b[t];
    int base = blockIdx.x * 256;
    for (int e = t; e < 2304; e += 256) nsh[e] = neigh[base * 9 + e];
    __syncthreads();
    float f[9];
#pragma unroll
    for (int k = 0; k < 9; ++k) { int j = nsh[t * 9 + k]; f[k] = (j < 0) ? 0.0f : feat[j]; }
    unsigned int ov[8];
#pragma unroll
    for (int co = 0; co < 16; ++co) {
        float a = bs[co];
#pragma unroll
        for (int k = 0; k < 9; ++k) a += f[k] * ws[co * 9 + k];
        a = fmaxf(a, 0.0f);
        unsigned short u = f2bf(a);
        if (co & 1) ov[co >> 1] |= ((unsigned int)u) << 16; else ov[co >> 1] = u;
    }
    uint4* dst = (uint4*)(out + (size_t)(base + t) * 16);
    dst[0] = make_uint4(ov[0], ov[1], ov[2], ov[3]);
    dst[1] = make_uint4(ov[4], ov[5], ov[6], ov[7]);
}

// ---------------- pool: u16-max over child range (values are post-relu, >=0) ----------------
template <int CIN>
__global__ __launch_bounds__(256) void pool_kernel(
    const unsigned short* __restrict__ x, const int* __restrict__ pidx, int nchild,
    unsigned short* __restrict__ out, int nparent)
{
    int p = blockIdx.x * 256 + threadIdx.x;
    if (p >= nparent) return;
    int lo = 0, hi = nchild;
    while (lo < hi) { int m = (lo + hi) >> 1; if (pidx[m] < p) lo = m + 1; else hi = m; }
    int s = lo;
    hi = nchild;
    while (lo < hi) { int m = (lo + hi) >> 1; if (pidx[m] < p + 1) lo = m + 1; else hi = m; }
    int e = lo;
    unsigned int acc[CIN / 2];
#pragma unroll
    for (int v = 0; v < CIN / 2; ++v) acc[v] = 0u;
    for (int j = s; j < e; ++j) {
        const unsigned int* r = (const unsigned int*)(x + (size_t)j * CIN);
#pragma unroll
        for (int v = 0; v < CIN / 2; ++v) {
            unsigned int a = r[v];
            unsigned int l = umax32(acc[v] & 0xffffu, a & 0xffffu);
            unsigned int h = umax32(acc[v] >> 16, a >> 16);
            acc[v] = l | (h << 16);
        }
    }
    unsigned int* o = (unsigned int*)(out + (size_t)p * CIN);
#pragma unroll
    for (int v = 0; v < CIN / 2; ++v) o[v] = acc[v];
}

// ---------------- generic MFMA conv: gather-im2col x [COUT,9*CIN] bf16 weights ----------------
// One block = 4 waves = 64 rows. A-fragments gathered directly from global (8 contiguous
// k-values always lie inside one neighbor's row since 8 | CIN). Optional fused unpool
// (gather src[pidx[neigh]]) and relu.
template <int CIN, int COUT, bool FUSE, bool RELU>
__global__ __launch_bounds__(256) void conv_mfma(
    const unsigned short* __restrict__ src, const int* __restrict__ neigh,
    const int* __restrict__ pidx, const unsigned short* __restrict__ wb,
    const float* __restrict__ bias, unsigned short* __restrict__ dst)
{
    constexpr int K  = 9 * CIN;
    constexpr int KT = (K + 31) / 32;
    constexpr int NT = COUT / 16;
    __shared__ int nsh[576];
    int t = threadIdx.x;
    int rowbase = blockIdx.x * 64;
    for (int e = t; e < 576; e += 256) {
        int j = neigh[(size_t)rowbase * 9 + e];
        if (FUSE) j = (j < 0) ? -1 : pidx[j];
        nsh[e] = j;
    }
    __syncthreads();
    int lane = t & 63;
    int wave = t >> 6;
    int m    = lane & 15;
    int quad = lane >> 4;
    int mrow = wave * 16 + m;   // row within block's 64
    floatx4 acc[NT];
#pragma unroll
    for (int n = 0; n < NT; ++n) acc[n] = (floatx4){0.f, 0.f, 0.f, 0.f};
    for (int kt = 0; kt < KT; ++kt) {
        int k0 = kt * 32 + quad * 8;
        bf16x8 a = zero_bf16x8();
        if (k0 < K) {
            int nb = k0 / CIN;
            int ci = k0 % CIN;
            int j  = nsh[mrow * 9 + nb];
            if (j >= 0) a = *(const bf16x8*)(src + (size_t)j * CIN + ci);
        }
#pragma unroll
        for (int n = 0; n < NT; ++n) {
            bf16x8 bfrag = zero_bf16x8();
            if (k0 < K) {
                int cout = n * 16 + m;
                bfrag = *(const bf16x8*)(wb + (size_t)cout * K + k0);
            }
            acc[n] = __builtin_amdgcn_mfma_f32_16x16x32_bf16(a, bfrag, acc[n], 0, 0, 0);
        }
    }
    // epilogue: D element (row = quad*4+r, col = m)
    int grow = rowbase + wave * 16 + quad * 4;
#pragma unroll
    for (int n = 0; n < NT; ++n) {
        int cout = n * 16 + m;
        float bv = bias[cout];
#pragma unroll
        for (int r = 0; r < 4; ++r) {
            float v = acc[n][r] + bv;
            if (RELU) v = fmaxf(v, 0.0f);
            dst[(size_t)(grow + r) * COUT + cout] = f2bf(v);
        }
    }
}

// ---------------- head: Cin=16 bf16 -> 1 fp32, no relu ----------------
static __device__ __forceinline__ float dot2(unsigned int u, const float* w) {
    return bf2f((unsigned short)(u & 0xffffu)) * w[0] + bf2f((unsigned short)(u >> 16)) * w[1];
}
__global__ __launch_bounds__(256) void head_kernel(
    const unsigned short* __restrict__ x, const int* __restrict__ neigh,
    const float* __restrict__ w, const float* __restrict__ b, float* __restrict__ out)
{
    __shared__ float ws[144];
    __shared__ int nsh[2304];
    int t = threadIdx.x;
    if (t < 144) ws[t] = w[t];
    int base = blockIdx.x * 256;
    for (int e = t; e < 2304; e += 256) nsh[e] = neigh[base * 9 + e];
    __syncthreads();
    float acc = b[0];
#pragma unroll
    for (int k = 0; k < 9; ++k) {
        int j = nsh[t * 9 + k];
        if (j >= 0) {
            const uint4* r = (const uint4*)(x + (size_t)j * 16);
            uint4 r0 = r[0], r1 = r[1];
            const float* wp = &ws[k * 16];
            acc += dot2(r0.x, wp)     + dot2(r0.y, wp + 2)  + dot2(r0.z, wp + 4)  + dot2(r0.w, wp + 6);
            acc += dot2(r1.x, wp + 8) + dot2(r1.y, wp + 10) + dot2(r1.z, wp + 12) + dot2(r1.w, wp + 14);
        }
    }
    out[base + t] = acc;
}

extern "C" void kernel_launch(void* const* d_in, const int* in_sizes, int n_in,
                              void* d_out, int out_size, void* d_ws, size_t ws_size,
                              hipStream_t stream) {
    const float* features = (const float*)d_in[0];
    const int* keys3   = (const int*)d_in[1];
    const int* keys2   = (const int*)d_in[2];
    const int* keys1   = (const int*)d_in[3];
    const int* neighs3 = (const int*)d_in[4];
    const int* neighs2 = (const int*)d_in[5];
    const int* neighs1 = (const int*)d_in[6];
    const float* w_enc1 = (const float*)d_in[7];
    const float* b_enc1 = (const float*)d_in[8];
    const float* w_enc2 = (const float*)d_in[9];
    const float* b_enc2 = (const float*)d_in[10];
    const float* w_enc3 = (const float*)d_in[11];
    const float* b_enc3 = (const float*)d_in[12];
    const float* w_dec1 = (const float*)d_in[13];
    const float* b_dec1 = (const float*)d_in[14];
    const float* w_dec2 = (const float*)d_in[15];
    const float* b_dec2 = (const float*)d_in[16];
    const float* w_head = (const float*)d_in[17];
    const float* b_head = (const float*)d_in[18];

    char* ws = (char*)d_ws;
    size_t off = 0;
    int* pidx32 = (int*)(ws + off);            off += (size_t)NN3 * 4;        // 1,048,576
    int* pidx21 = (int*)(ws + off);            off += (size_t)NN2 * 4;        //   262,144
    unsigned short* wb_enc2 = (unsigned short*)(ws + off); off += 4608 * 2;   //     9,216
    unsigned short* wb_enc3 = (unsigned short*)(ws + off); off += 18432 * 2;  //    36,864
    unsigned short* wb_dec1 = (unsigned short*)(ws + off); off += 18432 * 2;  //    36,864
    unsigned short* wb_dec2 = (unsigned short*)(ws + off); off += 4608 * 2;   //     9,216
    unsigned short* x8    = (unsigned short*)(ws + off); off += (size_t)NN3 * 16 * 2;
    unsigned short* x7p   = (unsigned short*)(ws + off); off += (size_t)NN2 * 16 * 2;
    unsigned short* x7    = (unsigned short*)(ws + off); off += (size_t)NN2 * 32 * 2;
    unsigned short* x6p   = (unsigned short*)(ws + off); off += (size_t)NN1 * 32 * 2;
    unsigned short* x6    = (unsigned short*)(ws + off); off += (size_t)NN1 * 64 * 2;
    unsigned short* x7dec = (unsigned short*)(ws + off); off += (size_t)NN2 * 32 * 2;
    unsigned short* x8dec = (unsigned short*)(ws + off); off += (size_t)NN3 * 16 * 2;

    // 1. prep: weight bf16 conversion + searchsorted parent indices
    prep_kernel<<<1460, 256, 0, stream>>>(w_enc2, w_enc3, w_dec1, w_dec2,
                                          wb_enc2, wb_enc3, wb_dec1, wb_dec2,
                                          keys3, keys2, keys1, pidx32, pidx21);
    // 2. enc1: [N3,1]f32 -> x8 [N3,16]bf16
    enc1_kernel<<<NN3 / 256, 256, 0, stream>>>(features, neighs3, w_enc1, b_enc1, x8);
    // 3. pool1: x8 -> x7p [N2,16]
    pool_kernel<16><<<NN2 / 256, 256, 0, stream>>>(x8, pidx32, NN3, x7p, NN2);
    // 4. enc2: x7p -> x7 [N2,32]
    conv_mfma<16, 32, false, true><<<NN2 / 64, 256, 0, stream>>>(x7p, neighs2, nullptr, wb_enc2, b_enc2, x7);
    // 5. pool2: x7 -> x6p [N1,32]
    pool_kernel<32><<<NN1 / 256, 256, 0, stream>>>(x7, pidx21, NN2, x6p, NN1);
    // 6. enc3: x6p -> x6 [N1,64]
    conv_mfma<32, 64, false, true><<<NN1 / 64, 256, 0, stream>>>(x6p, neighs1, nullptr, wb_enc3, b_enc3, x6);
    // 7. dec1 (fused unpool via pidx21): x6 -> x7dec [N2,32]
    conv_mfma<64, 32, true, true><<<NN2 / 64, 256, 0, stream>>>(x6, neighs2, pidx21, wb_dec1, b_dec1, x7dec);
    // 8. dec2 (fused unpool via pidx32): x7dec -> x8dec [N3,16]
    conv_mfma<32, 16, true, true><<<NN3 / 64, 256, 0, stream>>>(x7dec, neighs3, pidx32, wb_dec2, b_dec2, x8dec);
    // 9. head: x8dec -> out [N3,1]f32
    head_kernel<<<NN3 / 256, 256, 0, stream>>>(x8dec, neighs3, w_head, b_head, (float*)d_out);
}

// Round 2
// 208.415 us; speedup vs baseline: 1.1825x; 1.1825x over previous
//
#include <hip/hip_runtime.h>
#include <stdint.h>

#define NN3 262144
#define NN2 65536
#define NN1 16384

typedef __attribute__((ext_vector_type(8))) __bf16 bf16x8;
typedef __attribute__((ext_vector_type(4))) float floatx4;

static __device__ __forceinline__ float bf2f(unsigned short u) {
    union { unsigned int i; float f; } v; v.i = ((unsigned int)u) << 16; return v.f;
}
static __device__ __forceinline__ unsigned short f2bf(float f) {
    union { float f; unsigned int i; } v; v.f = f;
    unsigned int x = v.i;
    return (unsigned short)((x + 0x7fffu + ((x >> 16) & 1u)) >> 16);
}
static __device__ __forceinline__ bf16x8 zero_bf16x8() {
    bf16x8 z;
#pragma unroll
    for (int i = 0; i < 8; ++i) z[i] = (__bf16)0.0f;
    return z;
}

// ---------------- prep: convert conv weights fp32 -> bf16 (46080 elements) ----------------
__global__ __launch_bounds__(256) void prep_kernel(
    const float* __restrict__ w_enc2, const float* __restrict__ w_enc3,
    const float* __restrict__ w_dec1, const float* __restrict__ w_dec2,
    unsigned short* __restrict__ wb_enc2, unsigned short* __restrict__ wb_enc3,
    unsigned short* __restrict__ wb_dec1, unsigned short* __restrict__ wb_dec2)
{
    int t = blockIdx.x * 256 + threadIdx.x;
    if (t < 4608)  { wb_enc2[t] = f2bf(w_enc2[t]); return; }
    t -= 4608;
    if (t < 18432) { wb_enc3[t] = f2bf(w_enc3[t]); return; }
    t -= 18432;
    if (t < 18432) { wb_dec1[t] = f2bf(w_dec1[t]); return; }
    t -= 18432;
    if (t < 4608)  { wb_dec2[t] = f2bf(w_dec2[t]); }
}

// ---------------- enc1 + pool1 fused: [N3,1]f32 -> conv16 -> relu -> 4:1 max -> x7p [N2,16]bf16
// Pool exploits arange keys: parent(j) = j>>2, so the 4 children of a parent are
// 4 consecutive rows = 4 consecutive lanes. Pool = 2 shuffle-max rounds in fp32.
__global__ __launch_bounds__(256) void enc1pool_kernel(
    const float* __restrict__ feat, const int* __restrict__ neigh,
    const float* __restrict__ w, const float* __restrict__ b,
    unsigned short* __restrict__ x7p)
{
    __shared__ float ws[144];
    __shared__ float bs[16];
    __shared__ int nsh[2304];
    int t = threadIdx.x;
    if (t < 144) ws[t] = w[t];
    if (t < 16)  bs[t] = b[t];
    int base = blockIdx.x * 256;
    for (int e = t; e < 2304; e += 256) nsh[e] = neigh[(size_t)base * 9 + e];
    __syncthreads();
    float f[9];
#pragma unroll
    for (int k = 0; k < 9; ++k) { int j = nsh[t * 9 + k]; f[k] = (j < 0) ? 0.0f : feat[j]; }
    float v[16];
#pragma unroll
    for (int co = 0; co < 16; ++co) {
        float a = bs[co];
#pragma unroll
        for (int k = 0; k < 9; ++k) a += f[k] * ws[co * 9 + k];
        v[co] = fmaxf(a, 0.0f);
    }
    // pool over 4 consecutive lanes (fp32, pre-rounding)
#pragma unroll
    for (int co = 0; co < 16; ++co) {
        v[co] = fmaxf(v[co], __shfl_xor(v[co], 1));
        v[co] = fmaxf(v[co], __shfl_xor(v[co], 2));
    }
    if ((t & 3) == 0) {
        unsigned int ov[8];
#pragma unroll
        for (int h = 0; h < 8; ++h)
            ov[h] = (unsigned int)f2bf(v[2 * h]) | (((unsigned int)f2bf(v[2 * h + 1])) << 16);
        uint4* dst = (uint4*)(x7p + (size_t)((base + t) >> 2) * 16);
        dst[0] = make_uint4(ov[0], ov[1], ov[2], ov[3]);
        dst[1] = make_uint4(ov[4], ov[5], ov[6], ov[7]);
    }
}

// ---------------- generic MFMA conv ----------------
// One block = 4 waves = 64 rows. A-fragments gathered directly from global (8 contiguous
// k-values lie inside one neighbor row since 8 | CIN).
// SHIFT: gather src[neigh>>2] (fused unpool, arange keys). POOL: epilogue does 4:1 row max
// (a lane's 4 acc elements are rows quad*4..quad*4+3 = one parent's children).
template <int CIN, int COUT, bool SHIFT, bool POOL>
__global__ __launch_bounds__(256) void conv_mfma(
    const unsigned short* __restrict__ src, const int* __restrict__ neigh,
    const unsigned short* __restrict__ wb, const float* __restrict__ bias,
    unsigned short* __restrict__ dst)
{
    constexpr int K  = 9 * CIN;
    constexpr int KT = (K + 31) / 32;
    constexpr int NT = COUT / 16;
    __shared__ int nsh[576];
    int t = threadIdx.x;
    int rowbase = blockIdx.x * 64;
    for (int e = t; e < 576; e += 256) {
        int j = neigh[(size_t)rowbase * 9 + e];
        if (SHIFT) j = (j < 0) ? -1 : (j >> 2);
        nsh[e] = j;
    }
    __syncthreads();
    int lane = t & 63;
    int wave = t >> 6;
    int m    = lane & 15;
    int quad = lane >> 4;
    int mrow = wave * 16 + m;   // row within block's 64
    floatx4 acc[NT];
#pragma unroll
    for (int n = 0; n < NT; ++n) acc[n] = (floatx4){0.f, 0.f, 0.f, 0.f};
#pragma unroll
    for (int kt = 0; kt < KT; ++kt) {
        int k0 = kt * 32 + quad * 8;
        bf16x8 a = zero_bf16x8();
        if (k0 < K) {
            int nb = k0 / CIN;
            int ci = k0 % CIN;
            int j  = nsh[mrow * 9 + nb];
            if (j >= 0) a = *(const bf16x8*)(src + (size_t)j * CIN + ci);
        }
#pragma unroll
        for (int n = 0; n < NT; ++n) {
            bf16x8 bfrag = zero_bf16x8();
            if (k0 < K) bfrag = *(const bf16x8*)(wb + (size_t)(n * 16 + m) * K + k0);
            acc[n] = __builtin_amdgcn_mfma_f32_16x16x32_bf16(a, bfrag, acc[n], 0, 0, 0);
        }
    }
    if (POOL) {
        // parent row: one per (wave,quad)
        int p = (rowbase >> 2) + wave * 4 + quad;
#pragma unroll
        for (int n = 0; n < NT; ++n) {
            int cout = n * 16 + m;
            float vm = fmaxf(fmaxf(acc[n][0], acc[n][1]), fmaxf(acc[n][2], acc[n][3]));
            float v  = fmaxf(vm + bias[cout], 0.0f);
            dst[(size_t)p * COUT + cout] = f2bf(v);
        }
    } else {
        int grow = rowbase + wave * 16 + quad * 4;
#pragma unroll
        for (int n = 0; n < NT; ++n) {
            int cout = n * 16 + m;
            float bv = bias[cout];
#pragma unroll
            for (int r = 0; r < 4; ++r) {
                float v = fmaxf(acc[n][r] + bv, 0.0f);
                dst[(size_t)(grow + r) * COUT + cout] = f2bf(v);
            }
        }
    }
}

// ---------------- head: Cin=16 bf16 -> 1 fp32, no relu ----------------
static __device__ __forceinline__ float dot2(unsigned int u, const float* w) {
    return bf2f((unsigned short)(u & 0xffffu)) * w[0] + bf2f((unsigned short)(u >> 16)) * w[1];
}
__global__ __launch_bounds__(256) void head_kernel(
    const unsigned short* __restrict__ x, const int* __restrict__ neigh,
    const float* __restrict__ w, const float* __restrict__ b, float* __restrict__ out)
{
    __shared__ float ws[144];
    __shared__ int nsh[2304];
    int t = threadIdx.x;
    if (t < 144) ws[t] = w[t];
    int base = blockIdx.x * 256;
    for (int e = t; e < 2304; e += 256) nsh[e] = neigh[(size_t)base * 9 + e];
    __syncthreads();
    float acc = b[0];
#pragma unroll
    for (int k = 0; k < 9; ++k) {
        int j = nsh[t * 9 + k];
        if (j >= 0) {
            const uint4* r = (const uint4*)(x + (size_t)j * 16);
            uint4 r0 = r[0], r1 = r[1];
            const float* wp = &ws[k * 16];
            acc += dot2(r0.x, wp)     + dot2(r0.y, wp + 2)  + dot2(r0.z, wp + 4)  + dot2(r0.w, wp + 6);
            acc += dot2(r1.x, wp + 8) + dot2(r1.y, wp + 10) + dot2(r1.z, wp + 12) + dot2(r1.w, wp + 14);
        }
    }
    out[base + t] = acc;
}

extern "C" void kernel_launch(void* const* d_in, const int* in_sizes, int n_in,
                              void* d_out, int out_size, void* d_ws, size_t ws_size,
                              hipStream_t stream) {
    const float* features = (const float*)d_in[0];
    const int* neighs3 = (const int*)d_in[4];
    const int* neighs2 = (const int*)d_in[5];
    const int* neighs1 = (const int*)d_in[6];
    const float* w_enc1 = (const float*)d_in[7];
    const float* b_enc1 = (const float*)d_in[8];
    const float* w_enc2 = (const float*)d_in[9];
    const float* b_enc2 = (const float*)d_in[10];
    const float* w_enc3 = (const float*)d_in[11];
    const float* b_enc3 = (const float*)d_in[12];
    const float* w_dec1 = (const float*)d_in[13];
    const float* b_dec1 = (const float*)d_in[14];
    const float* w_dec2 = (const float*)d_in[15];
    const float* b_dec2 = (const float*)d_in[16];
    const float* w_head = (const float*)d_in[17];
    const float* b_head = (const float*)d_in[18];

    char* ws = (char*)d_ws;
    size_t off = 0;
    unsigned short* wb_enc2 = (unsigned short*)(ws + off); off += 4608 * 2;
    unsigned short* wb_enc3 = (unsigned short*)(ws + off); off += 18432 * 2;
    unsigned short* wb_dec1 = (unsigned short*)(ws + off); off += 18432 * 2;
    unsigned short* wb_dec2 = (unsigned short*)(ws + off); off += 4608 * 2;
    unsigned short* x7p   = (unsigned short*)(ws + off); off += (size_t)NN2 * 16 * 2;
    unsigned short* x6p   = (unsigned short*)(ws + off); off += (size_t)NN1 * 32 * 2;
    unsigned short* x6    = (unsigned short*)(ws + off); off += (size_t)NN1 * 64 * 2;
    unsigned short* x7dec = (unsigned short*)(ws + off); off += (size_t)NN2 * 32 * 2;
    unsigned short* x8dec = (unsigned short*)(ws + off); off += (size_t)NN3 * 16 * 2;

    // 1. prep: weight bf16 conversion
    prep_kernel<<<180, 256, 0, stream>>>(w_enc2, w_enc3, w_dec1, w_dec2,
                                         wb_enc2, wb_enc3, wb_dec1, wb_dec2);
    // 2. enc1 + pool1: features -> x7p [N2,16]
    enc1pool_kernel<<<NN3 / 256, 256, 0, stream>>>(features, neighs3, w_enc1, b_enc1, x7p);
    // 3. enc2 + pool2: x7p -> x6p [N1,32]   (conv over N2 rows, pooled epilogue)
    conv_mfma<16, 32, false, true><<<NN2 / 64, 256, 0, stream>>>(x7p, neighs2, wb_enc2, b_enc2, x6p);
    // 4. enc3: x6p -> x6 [N1,64]
    conv_mfma<32, 64, false, false><<<NN1 / 64, 256, 0, stream>>>(x6p, neighs1, wb_enc3, b_enc3, x6);
    // 5. dec1 (fused unpool, gather x6[n>>2]): -> x7dec [N2,32]
    conv_mfma<64, 32, true, false><<<NN2 / 64, 256, 0, stream>>>(x6, neighs2, wb_dec1, b_dec1, x7dec);
    // 6. dec2 (fused unpool, gather x7dec[n>>2]): -> x8dec [N3,16]
    conv_mfma<32, 16, true, false><<<NN3 / 64, 256, 0, stream>>>(x7dec, neighs3, wb_dec2, b_dec2, x8dec);
    // 7. head: x8dec -> out [N3,1]f32
    head_kernel<<<NN3 / 256, 256, 0, stream>>>(x8dec, neighs3, w_head, b_head, (float*)d_out);
}